// Round 1
// baseline (483.339 us; speedup 1.0000x reference)
//
#include <hip/hip_runtime.h>
#include <math.h>

#define N_IMG 8
#define C_CH 19
#define H_IMG 512
#define W_IMG 1024
#define HW (H_IMG * W_IMG)          // 524288 = 2^19
#define NDS (N_IMG * 64 * 128)      // 65536 downsampled pixels
#define K_TH 3124                   // min(65536, 200000/64) - 1
#define THRESH_F 0.6f

#define GATHER_BLOCKS 256                      // 256*256 threads = 65536 ds pixels
#define MAIN_BLOCKS (N_IMG * HW / (4 * 256))   // 4096

typedef float  f32x4 __attribute__((ext_vector_type(4)));
typedef int    i32x4 __attribute__((ext_vector_type(4)));

// ---------------------------------------------------------------------------
// K1 fused: one kernel, two block ranges.
//
//  blocks [0, GATHER_BLOCKS): GATHER path. One thread per downsampled pixel
//    (n, j, i). Reads its 4 bilinear corners (19 channels each) straight from
//    predict, computes softmax prob at the nearest-pixel target label, lerps,
//    writes pred_s ONCE (no zero-init kernel, no atomics). These blocks are
//    dispatched FIRST so their ~80 MB of scattered reads overlap the 318 MB
//    stream of the main blocks.
//
//  blocks [GATHER_BLOCKS, ...): STREAMING path (unchanged math). Per-pixel
//    two-pass softmax, writes pred_full = prob at own target for K3.
//
// FP note: pred_s summation order differs from the reference by ulps; the
// threshold clamp at 0.6 (kth value ~0.005 << 0.6) makes the output exact.
// pred_full is computed in the identical order as before (bitwise stable).
// ---------------------------------------------------------------------------
__global__ __launch_bounds__(256) void k1_fused(const float* __restrict__ predict,
                                                const int* __restrict__ target,
                                                float* __restrict__ pred_full,
                                                float* __restrict__ pred_s) {
    if (blockIdx.x < GATHER_BLOCKS) {
        // ---- gather path: one thread per ds pixel ----
        int gid = blockIdx.x * 256 + threadIdx.x;   // [0, 65536)
        int i = gid & 127;
        int j = (gid >> 7) & 63;
        int n = gid >> 13;

        float yc = (float)j * (511.0f / 63.0f);
        int y0 = (int)yc; if (y0 > H_IMG - 1) y0 = H_IMG - 1;
        int y1 = min(y0 + 1, H_IMG - 1);
        float wy = yc - (float)y0;
        int yi = min((int)rintf(yc), H_IMG - 1);

        float xc = (float)i * (1023.0f / 127.0f);
        int x0 = (int)xc; if (x0 > W_IMG - 1) x0 = W_IMG - 1;
        int x1 = min(x0 + 1, W_IMG - 1);
        float wx = xc - (float)x0;
        int xi = min((int)rintf(xc), W_IMG - 1);

        int L = target[n * HW + yi * W_IMG + xi];
        if (L < 0) L = 0;

        const float* basep = predict + (size_t)n * C_CH * HW;
        float p[2][2];
        #pragma unroll
        for (int a = 0; a < 2; a++) {
            int y = a ? y1 : y0;
            #pragma unroll
            for (int b = 0; b < 2; b++) {
                int x = b ? x1 : x0;
                const float* bp = basep + y * W_IMG + x;
                float v[C_CH];
                float m = -INFINITY;
                #pragma unroll
                for (int c = 0; c < C_CH; c++) {
                    v[c] = bp[(size_t)c * HW];
                    m = fmaxf(m, v[c]);
                }
                float s = 0.0f, eL = 0.0f;
                #pragma unroll
                for (int c = 0; c < C_CH; c++) {
                    float e = expf(v[c] - m);
                    s += e;
                    if (c == L) eL = e;
                }
                p[a][b] = eL / s;
            }
        }
        float a0 = p[0][0] * (1.0f - wy) + p[1][0] * wy;
        float a1 = p[0][1] * (1.0f - wy) + p[1][1] * wy;
        pred_s[n * 8192 + j * 128 + i] = a0 * (1.0f - wx) + a1 * wx;
        return;
    }

    // ---- streaming path: 4 pixels/thread, read predict once ----
    int tid = (blockIdx.x - GATHER_BLOCKS) * 256 + threadIdx.x;
    int p = tid * 4;
    int n = p >> 19;            // / HW
    int o = p & (HW - 1);
    const float* base = predict + (size_t)n * C_CH * HW + o;

    i32x4 tg = *reinterpret_cast<const i32x4*>(target + p);

    f32x4 v[C_CH];
    f32x4 m = (f32x4)(-INFINITY);
    #pragma unroll
    for (int c = 0; c < C_CH; c++) {
        f32x4 x = __builtin_nontemporal_load(
            reinterpret_cast<const f32x4*>(base + (size_t)c * HW));
        v[c] = x;
        m.x = fmaxf(m.x, x.x); m.y = fmaxf(m.y, x.y);
        m.z = fmaxf(m.z, x.z); m.w = fmaxf(m.w, x.w);
    }
    f32x4 s = (f32x4)(0.0f);
    f32x4 et = (f32x4)(0.0f);
    #pragma unroll
    for (int c = 0; c < C_CH; c++) {
        float ex = expf(v[c].x - m.x);
        float ey = expf(v[c].y - m.y);
        float ez = expf(v[c].z - m.z);
        float ew = expf(v[c].w - m.w);
        s.x += ex; s.y += ey; s.z += ez; s.w += ew;
        if (c == tg.x) et.x = ex;
        if (c == tg.y) et.y = ey;
        if (c == tg.z) et.z = ez;
        if (c == tg.w) et.w = ew;
    }
    f32x4 pf;
    pf.x = et.x / s.x; pf.y = et.y / s.y; pf.z = et.z / s.z; pf.w = et.w / s.w;
    *reinterpret_cast<f32x4*>(pred_full + p) = pf;   // regular store: L2/L3-hot for K3
}

// ---------------------------------------------------------------------------
// K2: exact k-th smallest of 65536 positive floats, 3-level radix select
// (11+11+10 bits) on the uint32 bit pattern (positive floats: uint order ==
// float order). Single block, 1024 threads (16 waves).
//   - per-WAVE privatized histograms (16 x 2048 bins = 128 KB LDS)
//   - parallel rank search: wave shuffle-scan + wave-offset sum
// ---------------------------------------------------------------------------
#define K2_THREADS 1024
#define K2_WAVES (K2_THREADS / 64)

__global__ __launch_bounds__(K2_THREADS) void k2_select(const float* __restrict__ pred_s,
                                                        float* __restrict__ thr_out) {
    __shared__ unsigned int hist[K2_WAVES * 2048];   // 128 KB
    __shared__ unsigned int tot[2048];               // 8 KB
    __shared__ unsigned int wsum[K2_WAVES];
    __shared__ unsigned int s_bin, s_k;

    const int t = threadIdx.x;
    const int lane = t & 63;
    const int wave = t >> 6;

    unsigned int prefix = 0;
    unsigned int k = K_TH;

    for (int lvl = 0; lvl < 3; lvl++) {
        const int nb = (lvl == 2) ? 1024 : 2048;

        for (int b = t; b < K2_WAVES * nb; b += K2_THREADS) hist[b] = 0;
        __syncthreads();

        unsigned int* myhist = &hist[wave * nb];
        for (int idx = t; idx < NDS; idx += K2_THREADS) {
            unsigned int u = __float_as_uint(pred_s[idx]);
            bool ok;
            unsigned int bin;
            if (lvl == 0)      { ok = true;                bin = u >> 21; }
            else if (lvl == 1) { ok = (u >> 21) == prefix; bin = (u >> 10) & 2047u; }
            else               { ok = (u >> 10) == prefix; bin = u & 1023u; }
            if (ok) atomicAdd(&myhist[bin], 1u);
        }
        __syncthreads();

        for (int b = t; b < nb; b += K2_THREADS) {
            unsigned int sm = 0;
            #pragma unroll
            for (int w = 0; w < K2_WAVES; w++) sm += hist[w * nb + b];
            tot[b] = sm;
        }
        __syncthreads();

        unsigned int c0, c1, s;
        if (nb == 2048) { c0 = tot[2 * t]; c1 = tot[2 * t + 1]; s = c0 + c1; }
        else            { c0 = tot[t];     c1 = 0;              s = c0; }

        unsigned int incl = s;
        #pragma unroll
        for (int off = 1; off < 64; off <<= 1) {
            unsigned int vv = (unsigned int)__shfl_up((int)incl, off, 64);
            if (lane >= off) incl += vv;
        }
        if (lane == 63) wsum[wave] = incl;
        __syncthreads();
        unsigned int woff = 0;
        for (int w = 0; w < wave; w++) woff += wsum[w];
        unsigned int excl = woff + incl - s;   // exclusive prefix of my chunk

        if (k >= excl && k < excl + s) {       // unique owner of rank k
            if (nb == 2048) {
                if (k < excl + c0) { s_bin = 2u * t;     s_k = k - excl; }
                else               { s_bin = 2u * t + 1; s_k = k - excl - c0; }
            } else {
                s_bin = (unsigned int)t; s_k = k - excl;
            }
        }
        __syncthreads();

        unsigned int b = s_bin;
        k = s_k;
        if (lvl == 0)      prefix = b;
        else if (lvl == 1) prefix = (prefix << 11) | b;
        else               prefix = (prefix << 10) | b;
        __syncthreads();
    }

    if (t == 0) {
        float kth = __uint_as_float(prefix);
        *thr_out = (kth > THRESH_F) ? kth : THRESH_F;
    }
}

// ---------------------------------------------------------------------------
// K3: light mask pass. pred_full + target (50 MB, mostly L2/L3-hot) -> out.
// ---------------------------------------------------------------------------
__global__ __launch_bounds__(256) void k3_mask(const float* __restrict__ pred_full,
                                               const int* __restrict__ target,
                                               const float* __restrict__ thr_ptr,
                                               int* __restrict__ out) {
    int tid = blockIdx.x * blockDim.x + threadIdx.x;
    int p = tid * 4;
    f32x4 pf = *reinterpret_cast<const f32x4*>(pred_full + p);
    i32x4 tg = *reinterpret_cast<const i32x4*>(target + p);
    float thr = *thr_ptr;
    i32x4 r;
    r.x = (pf.x <= thr && tg.x >= 0) ? tg.x : -1;
    r.y = (pf.y <= thr && tg.y >= 0) ? tg.y : -1;
    r.z = (pf.z <= thr && tg.z >= 0) ? tg.z : -1;
    r.w = (pf.w <= thr && tg.w >= 0) ? tg.w : -1;
    __builtin_nontemporal_store(r, reinterpret_cast<i32x4*>(out + p));
}

extern "C" void kernel_launch(void* const* d_in, const int* in_sizes, int n_in,
                              void* d_out, int out_size, void* d_ws, size_t ws_size,
                              hipStream_t stream) {
    const float* predict = (const float*)d_in[0];   // (8,19,512,1024) f32
    const int* target    = (const int*)d_in[1];     // (8,512,1024) i32
    int* out = (int*)d_out;

    // d_ws layout: [0] threshold (4 B) | [4096] pred_s (256 KB) | [1 MB] pred_full (16.8 MB)
    float* thr       = (float*)d_ws;
    float* pred_s    = (float*)((char*)d_ws + 4096);
    float* pred_full = (float*)((char*)d_ws + (1 << 20));

    hipLaunchKernelGGL(k1_fused, dim3(GATHER_BLOCKS + MAIN_BLOCKS), dim3(256), 0, stream,
                       predict, target, pred_full, pred_s);
    hipLaunchKernelGGL(k2_select, dim3(1), dim3(K2_THREADS), 0, stream, pred_s, thr);
    hipLaunchKernelGGL(k3_mask, dim3(N_IMG * HW / (4 * 256)), dim3(256), 0, stream,
                       pred_full, target, thr, out);
}